// Round 1
// baseline (413.673 us; speedup 1.0000x reference)
//
#include <hip/hip_runtime.h>
#include <math.h>

// Batched Thomas solve of A(exp(alpha)) u = f_rhs.
// alpha: [16384, 1024] f32, f_rhs: [1023] f32, out: [16384, 1023] f32.
//
// Round 1 design: thread-per-row. Coalescing fixed via LDS tiles (input
// staged col-major stride-65; output staged the same way). Forward-sweep
// intermediates (c, u) stored TRANSPOSED [e][B] in d_ws so all global
// traffic is coalesced. Faithful f32 math (expf + IEEE reciprocal) to sit
// far inside the ~2% relative accuracy threshold.

constexpr int BT   = 16384;  // total batch rows
constexpr int MPTS = 1024;   // K points per row
constexpr int NU   = 1023;   // unknowns per row (output cols)
constexpr int NC   = 1022;   // stored c/u entries (e = 0..1021)
constexpr int ROWS = 64;     // rows per block == block size (1 wave)
constexpr int CH   = 32;     // columns per staged chunk
constexpr int LSTR = 65;     // LDS col-major stride (floats): conflict-free

template <bool USE_WS>
__global__ __launch_bounds__(ROWS)
void thomas_kernel(const float* __restrict__ alpha,
                   const float* __restrict__ f_rhs,
                   float* __restrict__ out,
                   float* __restrict__ c_ws,
                   float* __restrict__ u_ws) {
    __shared__ float tile[CH * LSTR];  // col-major: tile[c*LSTR + r]
    __shared__ float f_lds[NU];

    const int t  = threadIdx.x;
    const int b0 = blockIdx.x * ROWS;
    const int b  = b0 + t;

    // Scratch fallback (only instantiated when USE_WS == false).
    float c_loc[USE_WS ? 1 : NC];
    float u_loc[USE_WS ? 1 : NC];

    // Stage f_rhs (shared by all rows) into LDS once.
    for (int i = t; i < NU; i += ROWS) f_lds[i] = f_rhs[i];

    const float h2 = (float)(1.0 / (1023.0 * 1023.0));

    float c_prev = 0.0f, u_prev = 0.0f, k_cur = 0.0f;

    auto store_cu = [&](int e, float c, float u) {
        if constexpr (USE_WS) {
            c_ws[(size_t)e * BT + b] = c;
            u_ws[(size_t)e * BT + b] = u;
        } else {
            c_loc[e] = c;
            u_loc[e] = u;
        }
    };

    auto step = [&](int e, float kn) {
        float denom = (k_cur + kn) + k_cur * c_prev;
        float r = 1.0f / denom;
        float c = -kn * r;
        float u = (f_lds[e] + k_cur * u_prev) * r;
        store_cu(e, c, u);
        c_prev = c; u_prev = u; k_cur = kn;
    };

    // ---------------- forward sweep ----------------
    for (int ci = 0; ci < 32; ++ci) {
        const int j0 = ci * CH;
        __syncthreads();  // protect tile reuse (also covers f_lds staging)

        // Cooperative staged load of K[j0 .. j0+31] for 64 rows, exp applied.
        // float4 per lane: 8 rows x 128B contiguous per instruction.
        for (int i = 0; i < 8; ++i) {
            int g  = i * 64 + t;     // float4 id in [0, 512)
            int r  = g >> 3;         // row 0..63
            int c4 = g & 7;          // float4 col 0..7
            const float4 v = *reinterpret_cast<const float4*>(
                &alpha[(size_t)(b0 + r) * MPTS + j0 + c4 * 4]);
            tile[(c4 * 4 + 0) * LSTR + r] = expf(v.x);
            tile[(c4 * 4 + 1) * LSTR + r] = expf(v.y);
            tile[(c4 * 4 + 2) * LSTR + r] = expf(v.z);
            tile[(c4 * 4 + 3) * LSTR + r] = expf(v.w);
        }
        __syncthreads();

        if (ci == 0) {
            k_cur = tile[0 * LSTR + t];      // K[0]
            float k1 = tile[1 * LSTR + t];   // K[1]
            float denom = 2.0f * k_cur + k1;
            float r = 1.0f / denom;
            c_prev = -k1 * r;
            u_prev = f_lds[0] * r;
            store_cu(0, c_prev, u_prev);
            k_cur = k1;
            for (int e = 1; e <= 30; ++e) {
                step(e, tile[(e + 1) * LSTR + t]);
            }
        } else {
            const int e_hi = (j0 + 30 < NC - 1) ? (j0 + 30) : (NC - 1);
            for (int e = j0 - 1; e <= e_hi; ++e) {
                step(e, tile[(e + 1 - j0) * LSTR + t]);
            }
        }
    }

    // e = 1022 (u_last): k_cur == K[1022] here (K[1023] is unused).
    float denom_l = k_cur + k_cur * c_prev;
    float u_last = (f_lds[1022] + k_cur * u_prev) / denom_l;

    // ---------------- back substitution ----------------
    float v_next = u_last;
    for (int ci = 31; ci >= 0; --ci) {
        const int j0 = ci * CH;
        __syncthreads();  // protect tile reuse vs previous cooperative writes

        if (ci == 31) {
            tile[30 * LSTR + t] = h2 * u_last;  // e = 1022 -> col 30
        }
        const int e_hi = (ci == 31) ? 1021 : (j0 + 31);
        for (int e = e_hi; e >= j0; --e) {
            float ce, ue;
            if constexpr (USE_WS) {
                ce = c_ws[(size_t)e * BT + b];
                ue = u_ws[(size_t)e * BT + b];
            } else {
                ce = c_loc[e];
                ue = u_loc[e];
            }
            float v = ue - ce * v_next;
            tile[(e - j0) * LSTR + t] = h2 * v;
            v_next = v;
        }
        __syncthreads();

        // Cooperative coalesced write: 2 rows x 128B per instruction.
        for (int i = 0; i < 32; ++i) {
            int g = i * 64 + t;
            int r = g >> 5;
            int c = g & 31;
            if (j0 + c < NU) {
                out[(size_t)(b0 + r) * NU + j0 + c] = tile[c * LSTR + r];
            }
        }
    }
}

extern "C" void kernel_launch(void* const* d_in, const int* in_sizes, int n_in,
                              void* d_out, int out_size, void* d_ws, size_t ws_size,
                              hipStream_t stream) {
    const float* alpha = (const float*)d_in[0];
    const float* f_rhs = (const float*)d_in[1];
    float* out = (float*)d_out;

    const size_t need = (size_t)2 * NC * BT * sizeof(float);  // ~134 MB
    dim3 grid(BT / ROWS), block(ROWS);

    if (ws_size >= need) {
        float* c_ws = (float*)d_ws;
        float* u_ws = c_ws + (size_t)NC * BT;
        thomas_kernel<true><<<grid, block, 0, stream>>>(alpha, f_rhs, out, c_ws, u_ws);
    } else {
        thomas_kernel<false><<<grid, block, 0, stream>>>(alpha, f_rhs, out,
                                                         nullptr, nullptr);
    }
}

// Round 3
// 45.369 us; speedup vs baseline: 9.1180x; 9.1180x over previous
//
#include <hip/hip_runtime.h>
#include <math.h>

// Batched tridiagonal solve A(exp(alpha)) u = f_rhs via chunked partition
// (SPIKE-style), one wave per row, all solver math in f64.
//
// System (n = 1023 unknowns, virtual identity row at j = 1023):
//   j=0:      b = 2K0+K1, a = 0,     d = -K1
//   1..1021:  b = Kj+Kj+1, a = -Kj,  d = -Kj+1
//   j=1022:   b = K1022,   a = -K1022, d = 0
//   j=1023:   b = 1, a = 0, d = 0, f = 0   (identity pad, u=0)
//
// Per lane (chunk of 16): forward elim -> (c',u~,v), backward -> (D,A,B) with
// u_i = D_i + A_i*uL + B_i*uR. Reduced 2-per-chunk boundary system solved with
// a 3x3 projective-matrix suffix scan (RENORMALIZED each step — round-2 NaN
// was m22 ~ 1e-70 flushing to 0 in fast_rcp's f32 seed) + affine prefix scan.

constexpr int BT   = 16384;
constexpr int MPTS = 1024;
constexpr int NU   = 1023;   // real unknowns
constexpr int CS   = 16;     // chunk size
constexpr int P    = 64;     // chunks per row == lanes per wave
constexpr int WPB  = 4;      // rows (waves) per block

__device__ __forceinline__ double fast_rcp(double x) {
    double r = (double)__builtin_amdgcn_rcpf((float)x);
    r = r * fma(-x, r, 2.0);   // NR 1
    r = r * fma(-x, r, 2.0);   // NR 2: ~f64 rounding
    return r;
}

__global__ __launch_bounds__(WPB * 64)
void pt_kernel(const float* __restrict__ alpha,
               const float* __restrict__ f_rhs,
               float* __restrict__ out) {
    const int t    = threadIdx.x;
    const int lane = t & 63;
    const int w    = t >> 6;
    const int row  = blockIdx.x * WPB + w;
    const int s    = lane * CS;          // first global index of this chunk

    __shared__ float ostage[WPB][NU + (NU >> 5) + 2];

    // ---------------- load K = exp(alpha) for this chunk (17 values) --------
    const float* arow = alpha + (size_t)row * MPTS;
    float kf[CS + 1];
    #pragma unroll
    for (int q = 0; q < 4; ++q) {
        const float4 v = *reinterpret_cast<const float4*>(arow + s + 4 * q);
        kf[4 * q + 0] = expf(v.x);
        kf[4 * q + 1] = expf(v.y);
        kf[4 * q + 2] = expf(v.z);
        kf[4 * q + 3] = expf(v.w);
    }
    {
        float kx = (lane < P - 1) ? arow[s + CS] : 0.0f;  // unused at lane 63
        kf[CS] = expf(kx);
    }

    // ---------------- load f for this chunk ---------------------------------
    float ff[CS];
    #pragma unroll
    for (int q = 0; q < 3; ++q) {
        const float4 v = *reinterpret_cast<const float4*>(f_rhs + s + 4 * q);
        ff[4 * q + 0] = v.x; ff[4 * q + 1] = v.y;
        ff[4 * q + 2] = v.z; ff[4 * q + 3] = v.w;
    }
    if (lane < P - 1) {
        const float4 v = *reinterpret_cast<const float4*>(f_rhs + s + 12);
        ff[12] = v.x; ff[13] = v.y; ff[14] = v.z; ff[15] = v.w;
    } else {
        ff[12] = f_rhs[1020]; ff[13] = f_rhs[1021]; ff[14] = f_rhs[1022];
        ff[15] = 0.0f;
    }

    // ---------------- phase 1a: in-chunk forward elimination ----------------
    // u_i = u~_i + v_i * u_{s-1} - c'_i * u_{i+1}
    double cA[CS], uA[CS], vA[CS];
    {
        double cp = 0.0, up = 0.0, vp = 1.0;  // vp=1 makes v_0 = -a_0/b_0
        #pragma unroll
        for (int i = 0; i < CS; ++i) {
            const int j = s + i;
            const double kc = (double)kf[i];
            const double kn = (double)kf[i + 1];
            double a, b, d;
            double f = (double)ff[i];
            if (j == 0)            { a = 0.0;  b = 2.0 * kc + kn; d = -kn; }
            else if (j == NU - 1)  { a = -kc;  b = kc;            d = 0.0; }
            else if (j == NU)      { a = 0.0;  b = 1.0;           d = 0.0; f = 0.0; }
            else                   { a = -kc;  b = kc + kn;       d = -kn; }
            const double den = fma(-a, cp, b);
            const double r   = fast_rcp(den);
            const double ci  = d * r;
            const double ui  = fma(-a, up, f) * r;
            const double vi  = (-a * vp) * r;
            cA[i] = ci; uA[i] = ui; vA[i] = vi;
            cp = ci; up = ui; vp = vi;
        }
    }

    // ---------------- phase 1b: in-chunk back substitution ------------------
    // u_i = D_i + A_i * uL + B_i * uR   (stored in place: uA=D, vA=A, cA=B)
    double De, Ae, Be;
    {
        double Dn = uA[CS - 1], An = vA[CS - 1], Bn = -cA[CS - 1];
        De = Dn; Ae = An; Be = Bn;
        uA[CS - 1] = Dn; vA[CS - 1] = An; cA[CS - 1] = Bn;
        #pragma unroll
        for (int i = CS - 2; i >= 0; --i) {
            const double ci = cA[i];
            Dn = fma(-ci, Dn, uA[i]);
            An = fma(-ci, An, vA[i]);
            Bn = -ci * Bn;
            uA[i] = Dn; vA[i] = An; cA[i] = Bn;
        }
    }
    const double Ds = uA[0], As = vA[0], Bs = cA[0];

    // ---------------- phase 2: reduced boundary system ----------------------
    // y_p = Ds + As*x_{p-1} + Bs*y_{p+1};  x_p = De + Ae*x_{p-1} + Be*y_{p+1}
    // Backward elimination (alpha,beta): projective 3x3 suffix scan,
    // renormalized by 1/m22 each step to keep the homogeneous scale ~1.
    double m00 = Bs;
    double m01 = fma(Bs, De, -(Ds * Be));
    double m02 = Ds;
    double m11 = fma(Bs, Ae, -(As * Be));
    double m12 = As;
    double m21 = -Be;
    double m22 = 1.0;

    #pragma unroll
    for (int dlt = 1; dlt < 64; dlt <<= 1) {
        const bool val = (lane + dlt) < 64;
        double b00 = __shfl_down(m00, dlt); b00 = val ? b00 : 1.0;
        double b01 = __shfl_down(m01, dlt); b01 = val ? b01 : 0.0;
        double b02 = __shfl_down(m02, dlt); b02 = val ? b02 : 0.0;
        double b11 = __shfl_down(m11, dlt); b11 = val ? b11 : 1.0;
        double b12 = __shfl_down(m12, dlt); b12 = val ? b12 : 0.0;
        double b21 = __shfl_down(m21, dlt); b21 = val ? b21 : 0.0;
        double b22 = __shfl_down(m22, dlt); b22 = val ? b22 : 1.0;
        const double n00 = m00 * b00;
        const double n01 = fma(m00, b01, fma(m01, b11, m02 * b21));
        const double n02 = fma(m00, b02, fma(m01, b12, m02 * b22));
        const double n11 = fma(m11, b11, m12 * b21);
        const double n12 = fma(m11, b12, m12 * b22);
        const double n21 = fma(m21, b11, m22 * b21);
        const double n22 = fma(m21, b12, m22 * b22);
        // Renormalize the projective state: n22 > 0 (physical coupling
        // margins keep it >= ~1e-5 of the entry scale). Keeps all entries
        // O(1) so f32-seeded rcp never sees a flushed-to-zero argument.
        const double rn = fast_rcp(n22);
        m00 = n00 * rn; m01 = n01 * rn; m02 = n02 * rn;
        m11 = n11 * rn; m12 = n12 * rn;
        m21 = n21 * rn; m22 = n22 * rn;
    }
    // (alpha_p, beta_p): y_p = alpha_p + beta_p * x_{p-1}
    const double rmm = fast_rcp(m22);   // m22 ~= 1 after renormalization
    const double alf = m02 * rmm;
    const double bet = m12 * rmm;
    double alfn = __shfl_down(alf, 1); alfn = (lane == 63) ? 0.0 : alfn;
    double betn = __shfl_down(bet, 1); betn = (lane == 63) ? 0.0 : betn;

    // x_p = dl + gm * x_{p-1}
    const double tt = fast_rcp(fma(-Be, betn, 1.0));
    const double dl = fma(Be, alfn, De) * tt;
    const double gm = Ae * tt;

    // Affine prefix scan for x (x_{-1} = 0).
    double X = dl, G = gm;
    #pragma unroll
    for (int dlt = 1; dlt < 64; dlt <<= 1) {
        double bx = __shfl_up(X, dlt);
        double bg = __shfl_up(G, dlt);
        const bool val = lane >= dlt;
        bx = val ? bx : 0.0;
        bg = val ? bg : 1.0;
        X = fma(G, bx, X);
        G = G * bg;
    }
    double xp = __shfl_up(X, 1);
    const double uL = (lane == 0) ? 0.0 : xp;          // u_{s-1}
    const double Y  = fma(bet, uL, alf);               // y_p = u_s
    double yn = __shfl_down(Y, 1);
    const double uR = (lane == 63) ? 0.0 : yn;         // u_e = y_{p+1}

    // ---------------- phase 3: recover interior + staged write --------------
    const double h2 = 1.0 / (1023.0 * 1023.0);
    float* ost = ostage[w];
    #pragma unroll
    for (int i = 0; i < CS; ++i) {
        const int j = s + i;
        const double uu = fma(vA[i], uL, fma(cA[i], uR, uA[i]));  // D + A*uL + B*uR
        if (j < NU) ost[j + (j >> 5)] = (float)(h2 * uu);
    }
    __syncthreads();

    float* orow = out + (size_t)row * NU;
    #pragma unroll
    for (int it = 0; it < 16; ++it) {
        const int c = it * 64 + lane;
        if (c < NU) orow[c] = ost[c + (c >> 5)];
    }
}

extern "C" void kernel_launch(void* const* d_in, const int* in_sizes, int n_in,
                              void* d_out, int out_size, void* d_ws, size_t ws_size,
                              hipStream_t stream) {
    const float* alpha = (const float*)d_in[0];
    const float* f_rhs = (const float*)d_in[1];
    float* out = (float*)d_out;

    dim3 grid(BT / WPB), block(WPB * 64);
    pt_kernel<<<grid, block, 0, stream>>>(alpha, f_rhs, out);
}

// Round 4
// 42.965 us; speedup vs baseline: 9.6281x; 1.0559x over previous
//
#include <hip/hip_runtime.h>
#include <math.h>

// Batched tridiagonal solve A(exp(alpha)) u = f_rhs via chunked partition
// (SPIKE-style), one wave per row, solver in f64. Round 4: op-level trims.
//  - fast_rcp: v_rcp_f64 + 1 NR (was f32 rcp + 2 NR)
//  - branchless phase-1a (boundaries folded into cp_init / kf pre-patch;
//    single cndmask at i==15)
//  - f_rhs in swizzled LDS (frees 16 VGPRs)
//  - projective scan kept normalized to m22 == 1 (6 entries, no final rcp)
//  - __launch_bounds__(256,3) to hold 3 waves/SIMD
// K path (expf on f32) is intentionally UNTOUCHED: observed absmax is set by
// f32-K quantization vs the np reference; solver rounding is 1e-13-level.

constexpr int BT   = 16384;
constexpr int MPTS = 1024;
constexpr int NU   = 1023;   // real unknowns
constexpr int CS   = 16;     // chunk size (per lane)
constexpr int WPB  = 4;      // rows (waves) per block

__device__ __forceinline__ double fast_rcp(double x) {
    double r = __builtin_amdgcn_rcp(x);       // v_rcp_f64, ~2^-27
    r = fma(r, fma(-x, r, 1.0), r);           // 1 NR -> ~2^-54
    return r;
}

__global__ __launch_bounds__(WPB * 64, 3)
void pt_kernel(const float* __restrict__ alpha,
               const float* __restrict__ f_rhs,
               float* __restrict__ out) {
    const int t    = threadIdx.x;
    const int lane = t & 63;
    const int w    = t >> 6;
    const int row  = blockIdx.x * WPB + w;
    const int s    = lane * CS;          // first global index of this chunk

    __shared__ float ostage[WPB][NU + (NU >> 5) + 2];
    __shared__ float f_lds[1056];        // swizzled: f[j] at j + (j>>5)

    // Stage f_rhs once per block (swizzled, 2-way-conflict-free reads).
    for (int i = t; i < NU; i += WPB * 64) f_lds[i + (i >> 5)] = f_rhs[i];
    if (t == 0) f_lds[1023 + (1023 >> 5)] = 0.0f;  // identity-pad row: f = 0

    // ---------------- load K = exp(alpha) for this chunk (17 values) --------
    const float* arow = alpha + (size_t)row * MPTS;
    float kf[CS + 1];
    #pragma unroll
    for (int q = 0; q < 4; ++q) {
        const float4 v = *reinterpret_cast<const float4*>(arow + s + 4 * q);
        kf[4 * q + 0] = expf(v.x);
        kf[4 * q + 1] = expf(v.y);
        kf[4 * q + 2] = expf(v.z);
        kf[4 * q + 3] = expf(v.w);
    }
    {
        float kx = (lane < 63) ? arow[s + CS] : 0.0f;  // lane63: exp(0)=1
        kf[CS] = expf(kx);
    }
    // lane 63 pre-patch: kn at j=1022 -> 0 gives b=kc, d=0 there; at j=1023
    // kc=0, kn=1 gives the identity row (b=1) with f=0.
    if (lane == 63) kf[15] = 0.0f;

    __syncthreads();  // f_lds ready

    // ---------------- phase 1a: in-chunk forward elimination ----------------
    // u_i = u~_i + v_i * uL - c'_i * u_{i+1}
    double cA[CS], uA[CS], vA[CS];
    {
        // cp_init = 1 for lane 0 folds the j=0 boundary (den = 2*K0 + K1).
        double cp = (lane == 0) ? 1.0 : 0.0;
        double up = 0.0, vp = 1.0;
        #pragma unroll
        for (int i = 0; i < CS; ++i) {
            const int j = s + i;
            const double kc = (double)kf[i];
            const double kn = (double)kf[i + 1];
            const double b  = kc + kn;
            const double f  = (double)f_lds[j + (j >> 5)];
            const double den = fma(kc, cp, b);
            const double r   = fast_rcp(den);
            double ci = -kn * r;
            const double ui = fma(kc, up, f) * r;
            const double vi = (kc * vp) * r;
            if (i == CS - 1) ci = (lane == 63) ? 0.0 : ci;  // identity pad row
            cA[i] = ci; uA[i] = ui; vA[i] = vi;
            cp = ci; up = ui; vp = vi;
        }
    }

    // ---------------- phase 1b: in-chunk back substitution ------------------
    // u_i = D_i + A_i * uL + B_i * uR   (stored in place: uA=D, vA=A, cA=B)
    double De, Ae, Be, Ds, As, Bs;
    {
        double Dn = uA[CS - 1], An = vA[CS - 1], Bn = -cA[CS - 1];
        De = Dn; Ae = An; Be = Bn;
        uA[CS - 1] = Dn; vA[CS - 1] = An; cA[CS - 1] = Bn;
        #pragma unroll
        for (int i = CS - 2; i >= 0; --i) {
            const double ci = cA[i];
            Dn = fma(-ci, Dn, uA[i]);
            An = fma(-ci, An, vA[i]);
            Bn = -ci * Bn;
            uA[i] = Dn; vA[i] = An; cA[i] = Bn;
        }
        Ds = uA[0]; As = vA[0]; Bs = cA[0];
    }

    // ---------------- phase 2: reduced boundary system ----------------------
    // y_p = Ds + As*x_{p-1} + Bs*y_{p+1};  x_p = De + Ae*x_{p-1} + Be*y_{p+1}
    // Projective 3x3 suffix scan, kept normalized so m22 == 1 (6 entries).
    double m00 = Bs;
    double m01 = fma(Bs, De, -(Ds * Be));
    double m02 = Ds;
    double m11 = fma(Bs, Ae, -(As * Be));
    double m12 = As;
    double m21 = -Be;

    #pragma unroll
    for (int dlt = 1; dlt < 64; dlt <<= 1) {
        const bool val = (lane + dlt) < 64;
        double b00 = __shfl_down(m00, dlt); b00 = val ? b00 : 1.0;
        double b01 = __shfl_down(m01, dlt); b01 = val ? b01 : 0.0;
        double b02 = __shfl_down(m02, dlt); b02 = val ? b02 : 0.0;
        double b11 = __shfl_down(m11, dlt); b11 = val ? b11 : 1.0;
        double b12 = __shfl_down(m12, dlt); b12 = val ? b12 : 0.0;
        double b21 = __shfl_down(m21, dlt); b21 = val ? b21 : 0.0;
        const double n00 = m00 * b00;
        const double n01 = fma(m00, b01, fma(m01, b11, m02 * b21));
        const double n02 = fma(m00, b02, fma(m01, b12, m02));   // b22 == 1
        const double n11 = fma(m11, b11, m12 * b21);
        const double n12 = fma(m11, b12, m12);
        const double n21 = fma(m21, b11, b21);                  // m22 == 1
        const double n22 = fma(m21, b12, 1.0);
        const double rn = fast_rcp(n22);   // n22 in (0,1]: strict dominance
        m00 = n00 * rn; m01 = n01 * rn; m02 = n02 * rn;
        m11 = n11 * rn; m12 = n12 * rn; m21 = n21 * rn;
    }
    // y_p = alf + bet * x_{p-1}   (m22 == 1)
    const double alf = m02;
    const double bet = m12;
    double alfn = __shfl_down(alf, 1); alfn = (lane == 63) ? 0.0 : alfn;
    double betn = __shfl_down(bet, 1); betn = (lane == 63) ? 0.0 : betn;

    // x_p = dl + gm * x_{p-1}
    const double tt = fast_rcp(fma(-Be, betn, 1.0));
    const double dl = fma(Be, alfn, De) * tt;
    const double gm = Ae * tt;

    // Affine prefix scan for x (x_{-1} = 0).
    double X = dl, G = gm;
    #pragma unroll
    for (int dlt = 1; dlt < 64; dlt <<= 1) {
        double bx = __shfl_up(X, dlt);
        double bg = __shfl_up(G, dlt);
        const bool val = lane >= dlt;
        bx = val ? bx : 0.0;
        bg = val ? bg : 1.0;
        X = fma(G, bx, X);
        G = G * bg;
    }
    double xp = __shfl_up(X, 1);
    const double uL = (lane == 0) ? 0.0 : xp;          // u_{s-1}
    const double Y  = fma(bet, uL, alf);               // y_p = u_s
    double yn = __shfl_down(Y, 1);
    const double uR = (lane == 63) ? 0.0 : yn;         // u_{e+1}

    // ---------------- phase 3: recover interior + staged write --------------
    const double h2 = 1.0 / (1023.0 * 1023.0);
    float* ost = ostage[w];
    #pragma unroll
    for (int i = 0; i < CS; ++i) {
        const int j = s + i;
        const double uu = fma(vA[i], uL, fma(cA[i], uR, uA[i]));
        if (j < NU) ost[j + (j >> 5)] = (float)(h2 * uu);
    }
    __syncthreads();

    float* orow = out + (size_t)row * NU;
    #pragma unroll
    for (int it = 0; it < 16; ++it) {
        const int c = it * 64 + lane;
        if (c < NU) orow[c] = ost[c + (c >> 5)];
    }
}

extern "C" void kernel_launch(void* const* d_in, const int* in_sizes, int n_in,
                              void* d_out, int out_size, void* d_ws, size_t ws_size,
                              hipStream_t stream) {
    const float* alpha = (const float*)d_in[0];
    const float* f_rhs = (const float*)d_in[1];
    float* out = (float*)d_out;

    dim3 grid(BT / WPB), block(WPB * 64);
    pt_kernel<<<grid, block, 0, stream>>>(alpha, f_rhs, out);
}